// Round 9
// baseline (196.390 us; speedup 1.0000x reference)
//
#include <hip/hip_runtime.h>
#include <math.h>

#define B_GRAPHS 4096
#define NPG 64
#define E_DIM 128
#define INV_B (1.0f / 4096.0f)
#define GPB 8      // graphs per block in kernel B
#define LDSW 129   // padded W row: read bank = (lane + f) % 32, conflict-free

static __device__ __forceinline__ float4 fmax4(float4 a, float4 b) {
    return make_float4(fmaxf(a.x, b.x), fmaxf(a.y, b.y),
                       fmaxf(a.z, b.z), fmaxf(a.w, b.w));
}

// ---------------------------------------------------------------------------
// Kernel A (unchanged, proven passing in R7): pure gather + segment-max.
// grid (4096, 2), 256 threads; one (graph, side) per block.
// ---------------------------------------------------------------------------
__global__ __launch_bounds__(256) void gather_pool_k(
    const int* __restrict__ lx, const int* __restrict__ rx,
    const float* __restrict__ emb, float* __restrict__ pooled)
{
    const int g    = blockIdx.x;
    const int side = blockIdx.y;
    const int t    = threadIdx.x;
    const int w    = t >> 6;
    const int lane = t & 63;

    __shared__ int   idx[NPG];
    __shared__ float red[4][E_DIM];   // SoA [component][w*32 + q]

    const int* __restrict__ x = side ? rx : lx;
    if (t < NPG) idx[t] = x[g * NPG + t];
    __syncthreads();

    const int n0 = t >> 5;
    const int q  = t & 31;
    const float4* __restrict__ e4 = reinterpret_cast<const float4*>(emb);

    float4 a = make_float4(-INFINITY, -INFINITY, -INFINITY, -INFINITY);
    #pragma unroll
    for (int i = 0; i < 8; ++i)
        a = fmax4(a, e4[(size_t)idx[(i << 3) + n0] * 32 + q]);

    a.x = fmaxf(a.x, __shfl_xor(a.x, 32));
    a.y = fmaxf(a.y, __shfl_xor(a.y, 32));
    a.z = fmaxf(a.z, __shfl_xor(a.z, 32));
    a.w = fmaxf(a.w, __shfl_xor(a.w, 32));

    if (lane < 32) {
        const int o = w * 32 + lane;
        red[0][o] = a.x; red[1][o] = a.y; red[2][o] = a.z; red[3][o] = a.w;
    }
    __syncthreads();

    if (t < 32) {
        float4 m;
        m.x = fmaxf(fmaxf(red[0][t],      red[0][32 + t]),
                    fmaxf(red[0][64 + t], red[0][96 + t]));
        m.y = fmaxf(fmaxf(red[1][t],      red[1][32 + t]),
                    fmaxf(red[1][64 + t], red[1][96 + t]));
        m.z = fmaxf(fmaxf(red[2][t],      red[2][32 + t]),
                    fmaxf(red[2][64 + t], red[2][96 + t]));
        m.w = fmaxf(fmaxf(red[3][t],      red[3][32 + t]),
                    fmaxf(red[3][64 + t], red[3][96 + t]));
        reinterpret_cast<float4*>(pooled)[((size_t)side * B_GRAPHS + g) * 32 + t] = m;
    }
}

// ---------------------------------------------------------------------------
// Kernel B v3: W-in-LDS matvec + cos + loss, <= 64 KB LDS (41 KB).
// 512 blocks x 256 thr, 8 graphs/block, one wave owns 2 graphs.
// W staged in TWO 64-row halves into Wl[64][129] (33 KB):
//   half h: lane L computes finals for e = h*64 + L, both sides,
//   accumulated in registers fin[gi][h][side] across halves.
// Hot loop per f: 1 W read (banks (L+f)%32, 2-way = free) + 2 broadcast
// P reads + 2 FMA. No LDS writes / barriers inside the f loop.
// ---------------------------------------------------------------------------
__global__ __launch_bounds__(256) void matvec_cos_k(
    const float* __restrict__ pooled, const float* __restrict__ W,
    const float* __restrict__ bias, const float* __restrict__ label,
    float* __restrict__ out)
{
    __shared__ float Wl[64 * LDSW];        // 33 KB (one half of W)
    __shared__ float P[GPB][2][E_DIM];     // 8 KB

    const int t    = threadIdx.x;
    const int g0   = blockIdx.x * GPB;
    const int w    = t >> 6;
    const int lane = t & 63;

    // ---- stage pooled for GPB graphs (coalesced float4) ----
    for (int i = t; i < GPB * 2 * E_DIM / 4; i += 256) {
        const int word = i * 4;
        const int g = word >> 8, s = (word >> 7) & 1, f = word & 127;
        const float4 v = reinterpret_cast<const float4*>(pooled)
            [(((size_t)s * B_GRAPHS + g0 + g) * E_DIM + f) >> 2];
        float* dst = &P[g][s][f];
        dst[0] = v.x; dst[1] = v.y; dst[2] = v.z; dst[3] = v.w;
    }

    float fin[2][2][2];   // [gi][h][side], fully unrolled -> registers

    #pragma unroll
    for (int h = 0; h < 2; ++h) {
        __syncthreads();   // h=0: nothing yet; h=1: protect Wl from readers
        // ---- stage W rows [h*64, h*64+64) ----
        for (int i = t; i < 64 * E_DIM / 4; i += 256) {
            const int word = i * 4;
            const int row = word >> 7, col = word & 127;
            const float4 v = reinterpret_cast<const float4*>(W)
                [((h * 64 + row) * E_DIM + col) >> 2];
            float* dst = &Wl[row * LDSW + col];
            dst[0] = v.x; dst[1] = v.y; dst[2] = v.z; dst[3] = v.w;
        }
        __syncthreads();   // W half (and, at h=0, P) staged

        const float be = bias[h * 64 + lane];
        const float* __restrict__ wr = &Wl[lane * LDSW];
        #pragma unroll
        for (int gi = 0; gi < 2; ++gi) {
            const int gg = gi * 4 + w;
            const float* __restrict__ p0 = &P[gg][0][0];
            const float* __restrict__ p1 = &P[gg][1][0];
            float fa = be, fb = be;
            #pragma unroll 8
            for (int f = 0; f < E_DIM; ++f) {
                const float wv = wr[f];
                fa = fmaf(p0[f], wv, fa);
                fb = fmaf(p1[f], wv, fb);
            }
            fin[gi][h][0] = fa;
            fin[gi][h][1] = fb;
        }
    }

    // ---- tail: per graph, in-wave reduce -> cos + loss ----
    #pragma unroll
    for (int gi = 0; gi < 2; ++gi) {
        const int gg = gi * 4 + w;
        float dot = fin[gi][0][0] * fin[gi][0][1] + fin[gi][1][0] * fin[gi][1][1];
        float nl  = fin[gi][0][0] * fin[gi][0][0] + fin[gi][1][0] * fin[gi][1][0];
        float nr  = fin[gi][0][1] * fin[gi][0][1] + fin[gi][1][1] * fin[gi][1][1];
        #pragma unroll
        for (int off = 1; off < 64; off <<= 1) {
            dot += __shfl_xor(dot, off);
            nl  += __shfl_xor(nl,  off);
            nr  += __shfl_xor(nr,  off);
        }
        if (lane == 0) {
            const int g = g0 + gg;
            const float nlv = fmaxf(sqrtf(nl), 1e-6f);
            const float nrv = fmaxf(sqrtf(nr), 1e-6f);
            const float c   = dot / (nlv * nrv);
            out[1 + g] = c;
            const float lab  = label[g];
            const float mm   = fmaxf(1.0f - c, 0.0f);
            const float loss = 0.5f * ((1.0f - lab) * c * c + lab * mm * mm);
            atomicAdd(out, loss * INV_B);
        }
    }
}

// ---------------------------------------------------------------------------
// Inputs (setup_inputs order):
// 0 left_x (N int32), 1 left_graph_index (B), 2 right_x (N), 3 right_graph_index,
// 4 left_x_batch (N), 5 right_x_batch (N), 6 label (B f32),
// 7 emb_table (V*E f32), 8 W (E*E f32), 9 b (E f32)
// Output: [0] = sim_loss, [1..B] = cos  (float32, out_size = B+1)
// ---------------------------------------------------------------------------
extern "C" void kernel_launch(void* const* d_in, const int* in_sizes, int n_in,
                              void* d_out, int out_size, void* d_ws, size_t ws_size,
                              hipStream_t stream)
{
    const int*   lx    = (const int*)d_in[0];
    const int*   rx    = (const int*)d_in[2];
    const float* label = (const float*)d_in[6];
    const float* emb   = (const float*)d_in[7];
    const float* W     = (const float*)d_in[8];
    const float* bias  = (const float*)d_in[9];

    float* out    = (float*)d_out;   // [0]=loss (atomic-accumulated), [1..B]=cos
    float* pooled = (float*)d_ws;    // [2][B_GRAPHS][E_DIM] = 4 MB

    hipMemsetAsync(out, 0, sizeof(float), stream);

    dim3 gA(B_GRAPHS, 2);
    gather_pool_k<<<gA, 256, 0, stream>>>(lx, rx, emb, pooled);
    matvec_cos_k<<<B_GRAPHS / GPB, 256, 0, stream>>>(pooled, W, bias, label, out);
}